// Round 4
// baseline (590.015 us; speedup 1.0000x reference)
//
#include <hip/hip_runtime.h>

// Median filter (k=22, REFLECT) + blend, NHWC (2,224,224,3) fp32.
// One wave per 8 consecutive-x pixels, processed as 4 pairs in lockstep.
// Window (484) in 8 regs/lane; ballot counting.
// V5 = V4 + two changes driven by occupancy/VALUBusy counters:
//  - WORK-STEALING persistent waves: grid = 2048 blocks (8192 waves = one
//    full residency at 36 VGPR); waves pull group ids from a global atomic
//    counter in d_ws (reset by hipMemsetAsync on-stream). Kills the 4.59-
//    round dispatch tail and probe-variance imbalance (Occupancy was 62%).
//  - BRACKET-FREE Newton probes: t = fma(d, -1/AREA, t), cap 12 iters, stop
//    at |d| <= DT. The peel is exact for ANY final (t, d) — candidates
//    {v<t} = RANK+d >= d+1 and {v>=t} = 242-d >= -d always — so dropping
//    the lo/hi bracket bookkeeping (~7 VALU/probe/pixel) preserves
//    bit-exactness; t cannot stall while d != 0 (monotone walk).
// Extraction: pair-packed q-counting sign-folded max-peel (proven absmax 0):
//    in-lane tree + bpermute-xor32 + ONE shared 5-stage ds_swizzle butterfly
//    (imm XOR patterns, zero address VALU) + readlane + eq-ballots + purge.
// Exact for any input incl. REFLECT duplicates.

#define HH 224
#define WW 224
#define CHN 3
#define KK 22
#define PT 10            // pad top/left; bottom/right = 11
#define AREA (KK * KK)   // 484
#define RANK 242         // median = 242nd smallest (1-indexed)
#define PXW 8
#define XGS (WW / PXW)   // 28
#define DT 2             // stop probing when |count-RANK| <= DT
#define NGROUPS (2 * CHN * HH * XGS)   // 37632

#define INFF  __int_as_float(0x7f800000)
#define NINFF __int_as_float(0xff800000)

__device__ __forceinline__ int reflect224(int g) {
    int a = abs(g);
    return min(a, 2 * (HH - 1) - a);
}

__device__ __forceinline__ int count8(const float v[8], float t) {
    int c = 0;
#pragma unroll
    for (int i = 0; i < 8; ++i)
        c += __popcll(__ballot(v[i] < t));
    return c;
}

// in-lane tree max over the 8 window regs
__device__ __forceinline__ float tree8(const float v[8]) {
    return fmaxf(fmaxf(fmaxf(v[0], v[1]), fmaxf(v[2], v[3])),
                 fmaxf(fmaxf(v[4], v[5]), fmaxf(v[6], v[7])));
}

// butterfly max within each 32-lane half (ds_swizzle BitMode XOR patterns:
// offset = (xor<<10) | 0x1F, no address VALU). Halves reduce independently.
__device__ __forceinline__ float half_bfly(float m) {
    m = fmaxf(m, __int_as_float(__builtin_amdgcn_ds_swizzle(__float_as_int(m), 0x401F))); // ^16
    m = fmaxf(m, __int_as_float(__builtin_amdgcn_ds_swizzle(__float_as_int(m), 0x201F))); // ^8
    m = fmaxf(m, __int_as_float(__builtin_amdgcn_ds_swizzle(__float_as_int(m), 0x101F))); // ^4
    m = fmaxf(m, __int_as_float(__builtin_amdgcn_ds_swizzle(__float_as_int(m), 0x081F))); // ^2
    m = fmaxf(m, __int_as_float(__builtin_amdgcn_ds_swizzle(__float_as_int(m), 0x041F))); // ^1
    return m;
}

__device__ __forceinline__ float bperm32(float x, int axor32) {
    return __int_as_float(
        __builtin_amdgcn_ds_bpermute(axor32, __float_as_int(x)));
}

__device__ __forceinline__ void gather(float v[8], const float* __restrict__ img,
                                       const int voff[8], int lane, int x) {
    if (x >= PT && x <= WW - 1 - (KK - 1 - PT)) {      // interior: x in [10,212]
        const float* base = img + (x - PT) * CHN;      // wave-uniform base
#pragma unroll
        for (int i = 0; i < 8; ++i) v[i] = base[voff[i]];
    } else {
#pragma unroll
        for (int i = 0; i < 8; ++i) {
            int s   = i * 64 + lane;
            int se  = min(s, AREA - 1);
            int row = se / KK;
            int col = se - row * KK;
            int gy672 = voff[i] - col * CHN;
            int gx = reflect224(x - PT + col);
            v[i] = img[gy672 + gx * CHN];
        }
    }
    v[7] = (lane < AREA - 448) ? v[7] : INFF;          // slots >= 484 -> +INF
}

__global__ __launch_bounds__(256)
void median_blend_kernel(const float* __restrict__ in,
                         const float* __restrict__ blend,
                         float* __restrict__ out,
                         int* __restrict__ ctr) {
    const int lane = threadIdx.x & 63;

    const float f = blend[0];
    const int axor32 = (lane ^ 32) << 2;        // hoisted bpermute byte addr
    const float ninf = NINFF;
    const float NINV = -1.0f / (float)AREA;     // Newton slope: -1/484

    float tprev = 0.5f;                          // persists across groups

#pragma unroll 1
    for (;;) {
        // ---- steal one 8-pixel group ----
        int wgv = 0;
        if (lane == 0) wgv = atomicAdd(ctr, 1);
        const int wg = __builtin_amdgcn_readfirstlane(wgv);
        if (wg >= NGROUPS) break;

        // wg = ((b*CHN + c)*HH + y)*XGS + xg
        const int xg = wg % XGS;
        const int t1 = wg / XGS;
        const int y  = t1 % HH;
        const int t2 = t1 / HH;
        const int c  = t2 % CHN;
        const int b  = t2 / CHN;

        const float* img  = in  + (size_t)b * (HH * WW * CHN) + c;
        float*       outp = out + (size_t)b * (HH * WW * CHN) + c;

        // per-group lane constants: voff = gy*672 + col*3 (vert reflect baked)
        int voff[8];
#pragma unroll
        for (int i = 0; i < 8; ++i) {
            int s   = i * 64 + lane;
            int se  = min(s, AREA - 1);
            int row = se / KK;
            int col = se - row * KK;
            int gy  = reflect224(y - PT + row);
            voff[i] = gy * (WW * CHN) + col * CHN;
        }

        const int x0 = xg * PXW;

#pragma unroll 1
        for (int j = 0; j < PXW; j += 2) {
            const int xA = x0 + j;
            const int xB = xA + 1;

            float vA[8], vB[8];
            gather(vA, img, voff, lane, xA);
            gather(vB, img, voff, lane, xB);

            // ---- warm-started bracket-free Newton probes, pair lockstep ----
            float tA = tprev, tB = tprev;
            int CA = count8(vA, tA);
            int CB = count8(vB, tB);
            int dA = CA - RANK, dB = CB - RANK;
            bool actA = (dA > DT || dA < -DT), actB = (dB > DT || dB < -DT);
#pragma unroll 1
            for (int it = 0; it < 12 && (actA || actB); ++it) {
                if (actA) {
                    tA = fmaf((float)dA, NINV, tA);
                    CA = count8(vA, tA);
                    dA = CA - RANK;
                    actA = (dA > DT || dA < -DT);
                }
                if (actB) {
                    tB = fmaf((float)dB, NINV, tB);
                    CB = count8(vB, tB);
                    dB = CB - RANK;
                    actB = (dB > DT || dB < -DT);
                }
            }

            // ---- pair-packed q-counting sign-folded max-peel ----
            // top (d>=0): (d+1)-th largest of {v<t};  bottom: (-d)-th smallest
            // of {v>=t} == peel max of -v. Exact for any (t,d).
            const bool topA = (dA >= 0), topB = (dB >= 0);
            int eA = topA ? dA + 1 : -dA;
            int eB = topB ? dB + 1 : -dB;
            const int sgnA = topA ? 0 : (int)0x80000000;
            const int sgnB = topB ? 0 : (int)0x80000000;
            if (topA) {                           // fold in place (uniform branch)
#pragma unroll
                for (int i = 0; i < 8; ++i) vA[i] = (vA[i] < tA) ? vA[i] : ninf;
            } else {
#pragma unroll
                for (int i = 0; i < 8; ++i) vA[i] = (vA[i] < tA) ? ninf : -vA[i];
            }
            if (topB) {
#pragma unroll
                for (int i = 0; i < 8; ++i) vB[i] = (vB[i] < tB) ? vB[i] : ninf;
            } else {
#pragma unroll
                for (int i = 0; i < 8; ++i) vB[i] = (vB[i] < tB) ? ninf : -vB[i];
            }
            // (+INF sentinels: top -> excluded; bottom -> fold to -INF, never
            //  selected since e <= #real candidates.)

            float medA = tA, medB = tB;           // provably overwritten
            bool doneA = false, doneB = false;
#pragma unroll 1
            for (int r = 0; r < 300 && !(doneA && doneB); ++r) {
                float pA = doneA ? ninf : tree8(vA);
                float pB = doneB ? ninf : tree8(vB);
                pA = fmaxf(pA, bperm32(pA, axor32));   // halves now symmetric
                pB = fmaxf(pB, bperm32(pB, axor32));
                float m = (lane < 32) ? pA : pB;  // pack A|B, one shared reduce
                m = half_bfly(m);
                const float mA = __int_as_float(
                    __builtin_amdgcn_readlane(__float_as_int(m), 0));
                const float mB = __int_as_float(
                    __builtin_amdgcn_readlane(__float_as_int(m), 32));
                if (!doneA) {
                    int q = 0;
#pragma unroll
                    for (int i = 0; i < 8; ++i)
                        q += __popcll(__ballot(vA[i] == mA));
                    if (eA <= q) {
                        medA = __int_as_float(__float_as_int(mA) ^ sgnA);
                        doneA = true;
                    } else {
                        eA -= q;
#pragma unroll
                        for (int i = 0; i < 8; ++i)
                            vA[i] = (vA[i] == mA) ? ninf : vA[i];
                    }
                }
                if (!doneB) {
                    int q = 0;
#pragma unroll
                    for (int i = 0; i < 8; ++i)
                        q += __popcll(__ballot(vB[i] == mB));
                    if (eB <= q) {
                        medB = __int_as_float(__float_as_int(mB) ^ sgnB);
                        doneB = true;
                    } else {
                        eB -= q;
#pragma unroll
                        for (int i = 0; i < 8; ++i)
                            vB[i] = (vB[i] == mB) ? ninf : vB[i];
                    }
                }
            }
            tprev = medB;                          // warm start for next pair

            // ---- blend + store ----
            const float xcA = img[y * (WW * CHN) + xA * CHN];
            const float xcB = img[y * (WW * CHN) + xB * CHN];
            if (lane == 0) {
                outp[y * (WW * CHN) + xA * CHN] = medA + f * (xcA - medA);
                outp[y * (WW * CHN) + xB * CHN] = medB + f * (xcB - medB);
            }
        }
    }
}

extern "C" void kernel_launch(void* const* d_in, const int* in_sizes, int n_in,
                              void* d_out, int out_size, void* d_ws, size_t ws_size,
                              hipStream_t stream) {
    const float* in    = (const float*)d_in[0];
    const float* blend = (const float*)d_in[1];
    float* out = (float*)d_out;
    int*   ctr = (int*)d_ws;

    hipMemsetAsync(ctr, 0, sizeof(int), stream);   // graph-capture-safe reset

    // one full residency: 256 CU x 8 blocks/CU (36 VGPR -> 8 waves/SIMD)
    const int nblocks = 2048;
    median_blend_kernel<<<nblocks, 256, 0, stream>>>(in, blend, out, ctr);
}

// Round 6
// 232.649 us; speedup vs baseline: 2.5361x; 2.5361x over previous
//
#include <hip/hip_runtime.h>

// Median filter (k=22, REFLECT) + blend, NHWC (2,224,224,3) fp32.
// One wave per 8 consecutive-x pixels, processed as 4 pairs in lockstep.
// Window (484) in 8 regs/lane; ballot counting.
// V6 = V4 + (no atomics — V5's single-counter atomicAdd serialized on
// cross-XCD cacheline bouncing: WRITE_SIZE 4x, VALUBusy 12%):
//  - PERSISTENT DETERMINISTIC CHUNKS: 8192 waves (2048 blocks), wave w owns
//    contiguous groups [w*N/8192, (w+1)*N/8192) — single full residency,
//    no dispatch tail, better tprev warm-start locality, zero sched traffic;
//  - BRACKET-FREE Newton probes (V5-proven exact): t = fma(d, -1/AREA, t),
//    cap 12, stop at |d| <= DT=1. Peel is exact for ANY final (t,d);
//  - e==1 FAST PATH in the peel: when only the max of candidates is needed,
//    skip eq-ballots + purge (q-counting only when e>1; exact w/ duplicates);
//  - BYTE-OFFSET gather: pre-scaled voffB + wave-uniform char* base ->
//    interior loads are bare global_load(saddr+voffset), no addr VALU.
// (V6.1: renamed byte-stride macro CB->XSB; it collided with the probe
//  counter variable CB and broke compilation.)
// Extraction core (proven absmax 0): pair-packed sign-folded max-peel with
// in-lane tree + bpermute-xor32 + ONE shared 5-stage ds_swizzle butterfly
// (imm XOR patterns, zero address VALU) + readlane broadcast.

#define HH 224
#define WW 224
#define CHN 3
#define KK 22
#define PT 10            // pad top/left; bottom/right = 11
#define AREA (KK * KK)   // 484
#define RANK 242         // median = 242nd smallest (1-indexed)
#define PXW 8
#define XGS (WW / PXW)   // 28
#define DT 1             // stop probing when |count-RANK| <= DT
#define NGROUPS (2 * CHN * HH * XGS)   // 37632
#define NWAVES 8192
#define XSB (CHN * 4)    // bytes per x-step (12)

#define INFF  __int_as_float(0x7f800000)
#define NINFF __int_as_float(0xff800000)

__device__ __forceinline__ int reflect224(int g) {
    int a = abs(g);
    return min(a, 2 * (HH - 1) - a);
}

__device__ __forceinline__ int count8(const float v[8], float t) {
    int c = 0;
#pragma unroll
    for (int i = 0; i < 8; ++i)
        c += __popcll(__ballot(v[i] < t));
    return c;
}

// in-lane tree max over the 8 window regs
__device__ __forceinline__ float tree8(const float v[8]) {
    return fmaxf(fmaxf(fmaxf(v[0], v[1]), fmaxf(v[2], v[3])),
                 fmaxf(fmaxf(v[4], v[5]), fmaxf(v[6], v[7])));
}

// butterfly max within each 32-lane half (ds_swizzle BitMode XOR patterns:
// offset = (xor<<10) | 0x1F, no address VALU). Halves reduce independently.
__device__ __forceinline__ float half_bfly(float m) {
    m = fmaxf(m, __int_as_float(__builtin_amdgcn_ds_swizzle(__float_as_int(m), 0x401F))); // ^16
    m = fmaxf(m, __int_as_float(__builtin_amdgcn_ds_swizzle(__float_as_int(m), 0x201F))); // ^8
    m = fmaxf(m, __int_as_float(__builtin_amdgcn_ds_swizzle(__float_as_int(m), 0x101F))); // ^4
    m = fmaxf(m, __int_as_float(__builtin_amdgcn_ds_swizzle(__float_as_int(m), 0x081F))); // ^2
    m = fmaxf(m, __int_as_float(__builtin_amdgcn_ds_swizzle(__float_as_int(m), 0x041F))); // ^1
    return m;
}

__device__ __forceinline__ float bperm32(float x, int axor32) {
    return __int_as_float(
        __builtin_amdgcn_ds_bpermute(axor32, __float_as_int(x)));
}

__device__ __forceinline__ float rdlane(float x, int l) {
    return __int_as_float(__builtin_amdgcn_readlane(__float_as_int(x), l));
}

// voffB holds BYTE offsets: gy*WW*CHN*4 + col*CHN*4 (vertical reflect baked)
__device__ __forceinline__ void gather(float v[8], const char* __restrict__ imgb,
                                       const int voffB[8], int lane, int x) {
    if (x >= PT && x <= WW - 1 - (KK - 1 - PT)) {      // interior: x in [10,212]
        const char* base = imgb + (x - PT) * XSB;      // wave-uniform base
#pragma unroll
        for (int i = 0; i < 8; ++i)
            v[i] = *(const float*)(base + voffB[i]);
    } else {
#pragma unroll
        for (int i = 0; i < 8; ++i) {
            int s   = i * 64 + lane;
            int se  = min(s, AREA - 1);
            int row = se / KK;
            int col = se - row * KK;
            int rowB = voffB[i] - col * XSB;
            int gx  = reflect224(x - PT + col);
            v[i] = *(const float*)(imgb + rowB + gx * XSB);
        }
    }
    v[7] = (lane < AREA - 448) ? v[7] : INFF;          // slots >= 484 -> +INF
}

__global__ __launch_bounds__(256)
void median_blend_kernel(const float* __restrict__ in,
                         const float* __restrict__ blend,
                         float* __restrict__ out) {
    const int lane = threadIdx.x & 63;
    const int wid  = threadIdx.x >> 6;
    const int w    = blockIdx.x * 4 + wid;       // 0..8191

    // contiguous deterministic chunk of 4-5 groups
    const int gstart = (int)(((long long)w * NGROUPS) >> 13);
    const int gend   = (int)(((long long)(w + 1) * NGROUPS) >> 13);

    const float f = blend[0];
    const int axor32 = (lane ^ 32) << 2;         // hoisted bpermute byte addr
    const float ninf = NINFF;
    const float NINV = -1.0f / (float)AREA;      // Newton slope: -1/484

    float tprev = 0.5f;                          // persists across groups

#pragma unroll 1
    for (int wg = gstart; wg < gend; ++wg) {
        // wg = ((b*CHN + c)*HH + y)*XGS + xg
        const int xg = wg % XGS;
        const int t1 = wg / XGS;
        const int y  = t1 % HH;
        const int t2 = t1 / HH;
        const int c  = t2 % CHN;
        const int b  = t2 / CHN;

        const float* img  = in  + (size_t)b * (HH * WW * CHN) + c;
        float*       outp = out + (size_t)b * (HH * WW * CHN) + c;
        const char*  imgb = (const char*)img;

        // per-group lane constants: BYTE voff = gy*2688 + col*12
        int voffB[8];
#pragma unroll
        for (int i = 0; i < 8; ++i) {
            int s   = i * 64 + lane;
            int se  = min(s, AREA - 1);
            int row = se / KK;
            int col = se - row * KK;
            int gy  = reflect224(y - PT + row);
            voffB[i] = gy * (WW * XSB) + col * XSB;
        }

        const int x0 = xg * PXW;

#pragma unroll 1
        for (int j = 0; j < PXW; j += 2) {
            const int xA = x0 + j;
            const int xB = xA + 1;

            float vA[8], vB[8];
            gather(vA, imgb, voffB, lane, xA);
            gather(vB, imgb, voffB, lane, xB);

            // ---- warm-started bracket-free Newton probes, pair lockstep ----
            float tA = tprev, tB = tprev;
            int CA = count8(vA, tA);
            int CBc = count8(vB, tB);
            int dA = CA - RANK, dB = CBc - RANK;
            bool actA = (dA > DT || dA < -DT), actB = (dB > DT || dB < -DT);
#pragma unroll 1
            for (int it = 0; it < 12 && (actA || actB); ++it) {
                if (actA) {
                    tA = fmaf((float)dA, NINV, tA);
                    CA = count8(vA, tA);
                    dA = CA - RANK;
                    actA = (dA > DT || dA < -DT);
                }
                if (actB) {
                    tB = fmaf((float)dB, NINV, tB);
                    CBc = count8(vB, tB);
                    dB = CBc - RANK;
                    actB = (dB > DT || dB < -DT);
                }
            }

            // ---- pair-packed q-counting sign-folded max-peel ----
            // top (d>=0): (d+1)-th largest of {v<t};  bottom: (-d)-th smallest
            // of {v>=t} == peel max of -v. Exact for any (t,d).
            const bool topA = (dA >= 0), topB = (dB >= 0);
            int eA = topA ? dA + 1 : -dA;
            int eB = topB ? dB + 1 : -dB;
            const int sgnA = topA ? 0 : (int)0x80000000;
            const int sgnB = topB ? 0 : (int)0x80000000;
            if (topA) {                           // fold in place (uniform branch)
#pragma unroll
                for (int i = 0; i < 8; ++i) vA[i] = (vA[i] < tA) ? vA[i] : ninf;
            } else {
#pragma unroll
                for (int i = 0; i < 8; ++i) vA[i] = (vA[i] < tA) ? ninf : -vA[i];
            }
            if (topB) {
#pragma unroll
                for (int i = 0; i < 8; ++i) vB[i] = (vB[i] < tB) ? vB[i] : ninf;
            } else {
#pragma unroll
                for (int i = 0; i < 8; ++i) vB[i] = (vB[i] < tB) ? ninf : -vB[i];
            }
            // (+INF sentinels: top -> excluded; bottom -> fold to -INF, never
            //  selected since e <= #real candidates.)

            float medA = tA, medB = tB;           // provably overwritten
            bool doneA = false, doneB = false;
#pragma unroll 1
            for (int r = 0; r < 300 && !(doneA && doneB); ++r) {
                float pA = doneA ? ninf : tree8(vA);
                float pB = doneB ? ninf : tree8(vB);
                pA = fmaxf(pA, bperm32(pA, axor32));   // halves now symmetric
                pB = fmaxf(pB, bperm32(pB, axor32));
                float m = (lane < 32) ? pA : pB;  // pack A|B, one shared reduce
                m = half_bfly(m);
                const float mA = rdlane(m, 0);
                const float mB = rdlane(m, 32);
                if (!doneA) {
                    if (eA == 1) {                // fast path: max IS the answer
                        medA = __int_as_float(__float_as_int(mA) ^ sgnA);
                        doneA = true;
                    } else {
                        int q = 0;
#pragma unroll
                        for (int i = 0; i < 8; ++i)
                            q += __popcll(__ballot(vA[i] == mA));
                        if (eA <= q) {
                            medA = __int_as_float(__float_as_int(mA) ^ sgnA);
                            doneA = true;
                        } else {
                            eA -= q;
#pragma unroll
                            for (int i = 0; i < 8; ++i)
                                vA[i] = (vA[i] == mA) ? ninf : vA[i];
                        }
                    }
                }
                if (!doneB) {
                    if (eB == 1) {
                        medB = __int_as_float(__float_as_int(mB) ^ sgnB);
                        doneB = true;
                    } else {
                        int q = 0;
#pragma unroll
                        for (int i = 0; i < 8; ++i)
                            q += __popcll(__ballot(vB[i] == mB));
                        if (eB <= q) {
                            medB = __int_as_float(__float_as_int(mB) ^ sgnB);
                            doneB = true;
                        } else {
                            eB -= q;
#pragma unroll
                            for (int i = 0; i < 8; ++i)
                                vB[i] = (vB[i] == mB) ? ninf : vB[i];
                        }
                    }
                }
            }
            tprev = medB;                          // warm start for next pair

            // ---- blend + store ----
            const float xcA = img[y * (WW * CHN) + xA * CHN];
            const float xcB = img[y * (WW * CHN) + xB * CHN];
            if (lane == 0) {
                outp[y * (WW * CHN) + xA * CHN] = medA + f * (xcA - medA);
                outp[y * (WW * CHN) + xB * CHN] = medB + f * (xcB - medB);
            }
        }
    }
}

extern "C" void kernel_launch(void* const* d_in, const int* in_sizes, int n_in,
                              void* d_out, int out_size, void* d_ws, size_t ws_size,
                              hipStream_t stream) {
    const float* in    = (const float*)d_in[0];
    const float* blend = (const float*)d_in[1];
    float* out = (float*)d_out;

    // one full residency: 2048 blocks x 4 waves = 8192 waves (36-44 VGPR)
    const int nblocks = NWAVES / 4;
    median_blend_kernel<<<nblocks, 256, 0, stream>>>(in, blend, out);
}

// Round 7
// 230.215 us; speedup vs baseline: 2.5629x; 1.0106x over previous
//
#include <hip/hip_runtime.h>

// Median filter (k=22, REFLECT) + blend, NHWC (2,224,224,3) fp32.
// One wave per 8 consecutive-x pixels, processed as TWO QUADS (4 pixels in
// lockstep). Window (484) in 8 regs/lane; ballot counting.
// V7 = V4 launch (one group per wave, 9408 blocks — V6's persistent chunks
// collapsed occupancy 62->28% and tripled WRITE_SIZE) + quad interleave:
//  - 4 pixels per iteration: two packed pair-reduces (A|B) and (C|D) run
//    independent 5-stage ds_swizzle butterflies whose DS latencies overlap;
//    gathers/folds/trees of 4 pixels issue back-to-back (4-way ILP);
//  - BRACKET-FREE Newton probes (V5/V6-proven exact): t = fma(d,-1/AREA,t),
//    cap 12, stop at |d| <= DT=1; peel is exact for ANY final (t,d);
//  - e==1 FAST PATH in the peel (V6-proven exact): max IS the answer, skip
//    eq-ballots/purge; q-counting only when e>1 (exact with duplicates);
//  - BYTE-OFFSET gather: pre-scaled voffB + wave-uniform char* base.
// Extraction core (proven absmax 0): sign-folded max-peel with in-lane tree
// + bpermute-xor32 + packed 5-stage ds_swizzle butterfly (imm XOR patterns,
// zero address VALU) + readlane broadcast.

#define HH 224
#define WW 224
#define CHN 3
#define KK 22
#define PT 10            // pad top/left; bottom/right = 11
#define AREA (KK * KK)   // 484
#define RANK 242         // median = 242nd smallest (1-indexed)
#define PXW 8
#define XGS (WW / PXW)   // 28
#define DT 1             // stop probing when |count-RANK| <= DT
#define NGROUPS (2 * CHN * HH * XGS)   // 37632
#define XSB (CHN * 4)    // bytes per x-step (12)

#define INFF  __int_as_float(0x7f800000)
#define NINFF __int_as_float(0xff800000)

__device__ __forceinline__ int reflect224(int g) {
    int a = abs(g);
    return min(a, 2 * (HH - 1) - a);
}

__device__ __forceinline__ int count8(const float v[8], float t) {
    int c = 0;
#pragma unroll
    for (int i = 0; i < 8; ++i)
        c += __popcll(__ballot(v[i] < t));
    return c;
}

// in-lane tree max over the 8 window regs
__device__ __forceinline__ float tree8(const float v[8]) {
    return fmaxf(fmaxf(fmaxf(v[0], v[1]), fmaxf(v[2], v[3])),
                 fmaxf(fmaxf(v[4], v[5]), fmaxf(v[6], v[7])));
}

// butterfly max within each 32-lane half (ds_swizzle BitMode XOR patterns:
// offset = (xor<<10) | 0x1F, no address VALU). Halves reduce independently.
__device__ __forceinline__ float half_bfly(float m) {
    m = fmaxf(m, __int_as_float(__builtin_amdgcn_ds_swizzle(__float_as_int(m), 0x401F))); // ^16
    m = fmaxf(m, __int_as_float(__builtin_amdgcn_ds_swizzle(__float_as_int(m), 0x201F))); // ^8
    m = fmaxf(m, __int_as_float(__builtin_amdgcn_ds_swizzle(__float_as_int(m), 0x101F))); // ^4
    m = fmaxf(m, __int_as_float(__builtin_amdgcn_ds_swizzle(__float_as_int(m), 0x081F))); // ^2
    m = fmaxf(m, __int_as_float(__builtin_amdgcn_ds_swizzle(__float_as_int(m), 0x041F))); // ^1
    return m;
}

__device__ __forceinline__ float bperm32(float x, int axor32) {
    return __int_as_float(
        __builtin_amdgcn_ds_bpermute(axor32, __float_as_int(x)));
}

__device__ __forceinline__ float rdlane(float x, int l) {
    return __int_as_float(__builtin_amdgcn_readlane(__float_as_int(x), l));
}

// voffB holds BYTE offsets: gy*WW*CHN*4 + col*CHN*4 (vertical reflect baked)
__device__ __forceinline__ void gather(float v[8], const char* __restrict__ imgb,
                                       const int voffB[8], int lane, int x) {
    if (x >= PT && x <= WW - 1 - (KK - 1 - PT)) {      // interior: x in [10,212]
        const char* base = imgb + (x - PT) * XSB;      // wave-uniform base
#pragma unroll
        for (int i = 0; i < 8; ++i)
            v[i] = *(const float*)(base + voffB[i]);
    } else {
#pragma unroll
        for (int i = 0; i < 8; ++i) {
            int s   = i * 64 + lane;
            int se  = min(s, AREA - 1);
            int row = se / KK;
            int col = se - row * KK;
            int rowB = voffB[i] - col * XSB;
            int gx  = reflect224(x - PT + col);
            v[i] = *(const float*)(imgb + rowB + gx * XSB);
        }
    }
    v[7] = (lane < AREA - 448) ? v[7] : INFF;          // slots >= 484 -> +INF
}

// one guarded bracket-free Newton probe step
#define PROBE(vX, tX, dX, actX)                         \
    if (actX) {                                         \
        tX = fmaf((float)dX, NINV, tX);                 \
        int cX_ = count8(vX, tX);                       \
        dX = cX_ - RANK;                                \
        actX = (dX > DT || dX < -DT);                   \
    }

// sign-fold in place: top (d>=0) keeps {v<t}; bottom keeps -{v>=t}
#define FOLD(vX, tX, topX)                                                   \
    if (topX) {                                                              \
        _Pragma("unroll")                                                    \
        for (int i_ = 0; i_ < 8; ++i_)                                       \
            vX[i_] = (vX[i_] < tX) ? vX[i_] : ninf;                          \
    } else {                                                                 \
        _Pragma("unroll")                                                    \
        for (int i_ = 0; i_ < 8; ++i_)                                       \
            vX[i_] = (vX[i_] < tX) ? ninf : -vX[i_];                         \
    }

// one peel resolution step for one pixel given its wave max mX
#define PEELSTEP(vX, eX, sgnX, medX, doneX, mX)                              \
    if (!doneX) {                                                            \
        if (eX == 1) {                                                       \
            medX = __int_as_float(__float_as_int(mX) ^ sgnX);                \
            doneX = true;                                                    \
        } else {                                                             \
            int q_ = 0;                                                      \
            _Pragma("unroll")                                                \
            for (int i_ = 0; i_ < 8; ++i_)                                   \
                q_ += __popcll(__ballot(vX[i_] == mX));                      \
            if (eX <= q_) {                                                  \
                medX = __int_as_float(__float_as_int(mX) ^ sgnX);            \
                doneX = true;                                                \
            } else {                                                         \
                eX -= q_;                                                    \
                _Pragma("unroll")                                            \
                for (int i_ = 0; i_ < 8; ++i_)                               \
                    vX[i_] = (vX[i_] == mX) ? ninf : vX[i_];                 \
            }                                                                \
        }                                                                    \
    }

__global__ __launch_bounds__(256)
void median_blend_kernel(const float* __restrict__ in,
                         const float* __restrict__ blend,
                         float* __restrict__ out) {
    const int lane = threadIdx.x & 63;
    const int wid  = threadIdx.x >> 6;
    const int wg = blockIdx.x * 4 + wid;        // wave-uniform group id
    // wg = ((b*CHN + c)*HH + y)*XGS + xg
    const int xg = wg % XGS;
    const int t1 = wg / XGS;
    const int y  = t1 % HH;
    const int t2 = t1 / HH;
    const int c  = t2 % CHN;
    const int b  = t2 / CHN;

    const float f = blend[0];
    const float* img  = in  + (size_t)b * (HH * WW * CHN) + c;
    float*       outp = out + (size_t)b * (HH * WW * CHN) + c;
    const char*  imgb = (const char*)img;

    // per-wave lane constants: BYTE voff = gy*2688 + col*12
    int voffB[8];
#pragma unroll
    for (int i = 0; i < 8; ++i) {
        int s   = i * 64 + lane;
        int se  = min(s, AREA - 1);
        int row = se / KK;
        int col = se - row * KK;
        int gy  = reflect224(y - PT + row);
        voffB[i] = gy * (WW * XSB) + col * XSB;
    }

    const int axor32 = (lane ^ 32) << 2;        // hoisted bpermute byte addr
    const float ninf = NINFF;
    const float NINV = -1.0f / (float)AREA;     // Newton slope: -1/484

    const int x0 = xg * PXW;
    float tprev = 0.5f;

#pragma unroll 1
    for (int j = 0; j < PXW; j += 4) {
        const int xA = x0 + j;
        const int xB = xA + 1;
        const int xC = xA + 2;
        const int xD = xA + 3;

        float vA[8], vB[8], vC[8], vD[8];
        gather(vA, imgb, voffB, lane, xA);
        gather(vB, imgb, voffB, lane, xB);
        gather(vC, imgb, voffB, lane, xC);
        gather(vD, imgb, voffB, lane, xD);

        // ---- warm-started bracket-free Newton probes, quad lockstep ----
        float tA = tprev, tB = tprev, tC = tprev, tD = tprev;
        int dA = count8(vA, tA) - RANK;
        int dB = count8(vB, tB) - RANK;
        int dC = count8(vC, tC) - RANK;
        int dD = count8(vD, tD) - RANK;
        bool actA = (dA > DT || dA < -DT), actB = (dB > DT || dB < -DT);
        bool actC = (dC > DT || dC < -DT), actD = (dD > DT || dD < -DT);
#pragma unroll 1
        for (int it = 0; it < 12 && (actA || actB || actC || actD); ++it) {
            PROBE(vA, tA, dA, actA)
            PROBE(vB, tB, dB, actB)
            PROBE(vC, tC, dC, actC)
            PROBE(vD, tD, dD, actD)
        }

        // ---- sign-folded max-peel, two packed pairs ----
        // top (d>=0): (d+1)-th largest of {v<t}; bottom: (-d)-th smallest of
        // {v>=t} == peel max of -v. Exact for any (t,d).
        const bool topA = (dA >= 0), topB = (dB >= 0);
        const bool topC = (dC >= 0), topD = (dD >= 0);
        int eA = topA ? dA + 1 : -dA;
        int eB = topB ? dB + 1 : -dB;
        int eC = topC ? dC + 1 : -dC;
        int eD = topD ? dD + 1 : -dD;
        const int sgnA = topA ? 0 : (int)0x80000000;
        const int sgnB = topB ? 0 : (int)0x80000000;
        const int sgnC = topC ? 0 : (int)0x80000000;
        const int sgnD = topD ? 0 : (int)0x80000000;
        FOLD(vA, tA, topA)
        FOLD(vB, tB, topB)
        FOLD(vC, tC, topC)
        FOLD(vD, tD, topD)
        // (+INF sentinels: top -> excluded; bottom -> fold to -INF, never
        //  selected since e <= #real candidates.)

        float medA = tA, medB = tB, medC = tC, medD = tD; // provably overwritten
        bool doneA = false, doneB = false, doneC = false, doneD = false;
#pragma unroll 1
        for (int r = 0; r < 300 && !(doneA && doneB && doneC && doneD); ++r) {
            float pA = doneA ? ninf : tree8(vA);
            float pB = doneB ? ninf : tree8(vB);
            float pC = doneC ? ninf : tree8(vC);
            float pD = doneD ? ninf : tree8(vD);
            pA = fmaxf(pA, bperm32(pA, axor32));   // halves now symmetric
            pB = fmaxf(pB, bperm32(pB, axor32));
            pC = fmaxf(pC, bperm32(pC, axor32));
            pD = fmaxf(pD, bperm32(pD, axor32));
            float m1 = (lane < 32) ? pA : pB;      // pack A|B
            float m2 = (lane < 32) ? pC : pD;      // pack C|D
            m1 = half_bfly(m1);                    // two independent DS chains
            m2 = half_bfly(m2);                    //   -> latencies overlap
            const float mA = rdlane(m1, 0);
            const float mB = rdlane(m1, 32);
            const float mC = rdlane(m2, 0);
            const float mD = rdlane(m2, 32);
            PEELSTEP(vA, eA, sgnA, medA, doneA, mA)
            PEELSTEP(vB, eB, sgnB, medB, doneB, mB)
            PEELSTEP(vC, eC, sgnC, medC, doneC, mC)
            PEELSTEP(vD, eD, sgnD, medD, doneD, mD)
        }
        tprev = medD;                              // warm start for next quad

        // ---- blend + store ----
        const float xcA = img[y * (WW * CHN) + xA * CHN];
        const float xcB = img[y * (WW * CHN) + xB * CHN];
        const float xcC = img[y * (WW * CHN) + xC * CHN];
        const float xcD = img[y * (WW * CHN) + xD * CHN];
        if (lane == 0) {
            outp[y * (WW * CHN) + xA * CHN] = medA + f * (xcA - medA);
            outp[y * (WW * CHN) + xB * CHN] = medB + f * (xcB - medB);
            outp[y * (WW * CHN) + xC * CHN] = medC + f * (xcC - medC);
            outp[y * (WW * CHN) + xD * CHN] = medD + f * (xcD - medD);
        }
    }
}

extern "C" void kernel_launch(void* const* d_in, const int* in_sizes, int n_in,
                              void* d_out, int out_size, void* d_ws, size_t ws_size,
                              hipStream_t stream) {
    const float* in    = (const float*)d_in[0];
    const float* blend = (const float*)d_in[1];
    float* out = (float*)d_out;

    const int nblocks = NGROUPS / 4;           // 9408, one group per wave
    median_blend_kernel<<<nblocks, 256, 0, stream>>>(in, blend, out);
}

// Round 8
// 176.892 us; speedup vs baseline: 3.3354x; 1.3014x over previous
//
#include <hip/hip_runtime.h>

// Median filter (k=22, REFLECT) + blend, NHWC (2,224,224,3) fp32.
// One wave per 8 consecutive-x pixels, processed as 4 PAIRS in lockstep.
// Window (484) in 8 regs/lane; ballot counting.
// V8 = clean recombination of counter-validated pieces:
//  - V4 SCHEDULING: one group per wave, 9408 blocks (occupancy 62%; V6/V7's
//    regressions were NOT scheduling — V7 kept this launch and still
//    collapsed, isolating the confound to DT=1);
//  - V5 PROBES: DT=2, bracket-free Newton t=fma(d,-1/AREA,t), cap 12.
//    DT=1 oscillates (cluster in a 2/484 band -> d=+2/-2 cycle, cap-out,
//    large residual |d|, latency-bound peel tail -> straggler waves).
//    DT=2's stop band can't be skipped; V5 busy-time 67us proves it.
//    Peel is exact for ANY final (t,d) so bracket removal is safe;
//  - V6 micro-cuts (absmax-0 proven): e==1 fast path in the peel;
//    byte-offset gather (pre-scaled voffB + wave-uniform char* base).
// Extraction core (proven absmax 0): pair-packed sign-folded max-peel with
// in-lane tree + bpermute-xor32 + ONE shared 5-stage ds_swizzle butterfly
// (imm XOR patterns, zero address VALU) + readlane broadcast.

#define HH 224
#define WW 224
#define CHN 3
#define KK 22
#define PT 10            // pad top/left; bottom/right = 11
#define AREA (KK * KK)   // 484
#define RANK 242         // median = 242nd smallest (1-indexed)
#define PXW 8
#define XGS (WW / PXW)   // 28
#define DT 2             // stop probing when |count-RANK| <= DT
#define NGROUPS (2 * CHN * HH * XGS)   // 37632
#define XSB (CHN * 4)    // bytes per x-step (12)

#define INFF  __int_as_float(0x7f800000)
#define NINFF __int_as_float(0xff800000)

__device__ __forceinline__ int reflect224(int g) {
    int a = abs(g);
    return min(a, 2 * (HH - 1) - a);
}

__device__ __forceinline__ int count8(const float v[8], float t) {
    int c = 0;
#pragma unroll
    for (int i = 0; i < 8; ++i)
        c += __popcll(__ballot(v[i] < t));
    return c;
}

// in-lane tree max over the 8 window regs
__device__ __forceinline__ float tree8(const float v[8]) {
    return fmaxf(fmaxf(fmaxf(v[0], v[1]), fmaxf(v[2], v[3])),
                 fmaxf(fmaxf(v[4], v[5]), fmaxf(v[6], v[7])));
}

// butterfly max within each 32-lane half (ds_swizzle BitMode XOR patterns:
// offset = (xor<<10) | 0x1F, no address VALU). Halves reduce independently.
__device__ __forceinline__ float half_bfly(float m) {
    m = fmaxf(m, __int_as_float(__builtin_amdgcn_ds_swizzle(__float_as_int(m), 0x401F))); // ^16
    m = fmaxf(m, __int_as_float(__builtin_amdgcn_ds_swizzle(__float_as_int(m), 0x201F))); // ^8
    m = fmaxf(m, __int_as_float(__builtin_amdgcn_ds_swizzle(__float_as_int(m), 0x101F))); // ^4
    m = fmaxf(m, __int_as_float(__builtin_amdgcn_ds_swizzle(__float_as_int(m), 0x081F))); // ^2
    m = fmaxf(m, __int_as_float(__builtin_amdgcn_ds_swizzle(__float_as_int(m), 0x041F))); // ^1
    return m;
}

__device__ __forceinline__ float bperm32(float x, int axor32) {
    return __int_as_float(
        __builtin_amdgcn_ds_bpermute(axor32, __float_as_int(x)));
}

__device__ __forceinline__ float rdlane(float x, int l) {
    return __int_as_float(__builtin_amdgcn_readlane(__float_as_int(x), l));
}

// voffB holds BYTE offsets: gy*WW*CHN*4 + col*CHN*4 (vertical reflect baked)
__device__ __forceinline__ void gather(float v[8], const char* __restrict__ imgb,
                                       const int voffB[8], int lane, int x) {
    if (x >= PT && x <= WW - 1 - (KK - 1 - PT)) {      // interior: x in [10,212]
        const char* base = imgb + (x - PT) * XSB;      // wave-uniform base
#pragma unroll
        for (int i = 0; i < 8; ++i)
            v[i] = *(const float*)(base + voffB[i]);
    } else {
#pragma unroll
        for (int i = 0; i < 8; ++i) {
            int s   = i * 64 + lane;
            int se  = min(s, AREA - 1);
            int row = se / KK;
            int col = se - row * KK;
            int rowB = voffB[i] - col * XSB;
            int gx  = reflect224(x - PT + col);
            v[i] = *(const float*)(imgb + rowB + gx * XSB);
        }
    }
    v[7] = (lane < AREA - 448) ? v[7] : INFF;          // slots >= 484 -> +INF
}

// one guarded bracket-free Newton probe step
#define PROBE(vX, tX, dX, actX)                         \
    if (actX) {                                         \
        tX = fmaf((float)dX, NINV, tX);                 \
        int cX_ = count8(vX, tX);                       \
        dX = cX_ - RANK;                                \
        actX = (dX > DT || dX < -DT);                   \
    }

// sign-fold in place: top (d>=0) keeps {v<t}; bottom keeps -{v>=t}
#define FOLD(vX, tX, topX)                                                   \
    if (topX) {                                                              \
        _Pragma("unroll")                                                    \
        for (int i_ = 0; i_ < 8; ++i_)                                       \
            vX[i_] = (vX[i_] < tX) ? vX[i_] : ninf;                          \
    } else {                                                                 \
        _Pragma("unroll")                                                    \
        for (int i_ = 0; i_ < 8; ++i_)                                       \
            vX[i_] = (vX[i_] < tX) ? ninf : -vX[i_];                         \
    }

// one peel resolution step for one pixel given its wave max mX
#define PEELSTEP(vX, eX, sgnX, medX, doneX, mX)                              \
    if (!doneX) {                                                            \
        if (eX == 1) {                                                       \
            medX = __int_as_float(__float_as_int(mX) ^ sgnX);                \
            doneX = true;                                                    \
        } else {                                                             \
            int q_ = 0;                                                      \
            _Pragma("unroll")                                                \
            for (int i_ = 0; i_ < 8; ++i_)                                   \
                q_ += __popcll(__ballot(vX[i_] == mX));                      \
            if (eX <= q_) {                                                  \
                medX = __int_as_float(__float_as_int(mX) ^ sgnX);            \
                doneX = true;                                                \
            } else {                                                         \
                eX -= q_;                                                    \
                _Pragma("unroll")                                            \
                for (int i_ = 0; i_ < 8; ++i_)                               \
                    vX[i_] = (vX[i_] == mX) ? ninf : vX[i_];                 \
            }                                                                \
        }                                                                    \
    }

__global__ __launch_bounds__(256)
void median_blend_kernel(const float* __restrict__ in,
                         const float* __restrict__ blend,
                         float* __restrict__ out) {
    const int lane = threadIdx.x & 63;
    const int wid  = threadIdx.x >> 6;
    const int wg = blockIdx.x * 4 + wid;        // wave-uniform group id
    // wg = ((b*CHN + c)*HH + y)*XGS + xg
    const int xg = wg % XGS;
    const int t1 = wg / XGS;
    const int y  = t1 % HH;
    const int t2 = t1 / HH;
    const int c  = t2 % CHN;
    const int b  = t2 / CHN;

    const float f = blend[0];
    const float* img  = in  + (size_t)b * (HH * WW * CHN) + c;
    float*       outp = out + (size_t)b * (HH * WW * CHN) + c;
    const char*  imgb = (const char*)img;

    // per-wave lane constants: BYTE voff = gy*2688 + col*12
    int voffB[8];
#pragma unroll
    for (int i = 0; i < 8; ++i) {
        int s   = i * 64 + lane;
        int se  = min(s, AREA - 1);
        int row = se / KK;
        int col = se - row * KK;
        int gy  = reflect224(y - PT + row);
        voffB[i] = gy * (WW * XSB) + col * XSB;
    }

    const int axor32 = (lane ^ 32) << 2;        // hoisted bpermute byte addr
    const float ninf = NINFF;
    const float NINV = -1.0f / (float)AREA;     // Newton slope: -1/484

    const int x0 = xg * PXW;
    float tprev = 0.5f;

#pragma unroll 1
    for (int j = 0; j < PXW; j += 2) {
        const int xA = x0 + j;
        const int xB = xA + 1;

        float vA[8], vB[8];
        gather(vA, imgb, voffB, lane, xA);
        gather(vB, imgb, voffB, lane, xB);

        // ---- warm-started bracket-free Newton probes, pair lockstep ----
        float tA = tprev, tB = tprev;
        int dA = count8(vA, tA) - RANK;
        int dB = count8(vB, tB) - RANK;
        bool actA = (dA > DT || dA < -DT), actB = (dB > DT || dB < -DT);
#pragma unroll 1
        for (int it = 0; it < 12 && (actA || actB); ++it) {
            PROBE(vA, tA, dA, actA)
            PROBE(vB, tB, dB, actB)
        }

        // ---- pair-packed sign-folded max-peel ----
        // top (d>=0): (d+1)-th largest of {v<t}; bottom: (-d)-th smallest of
        // {v>=t} == peel max of -v. Exact for any (t,d).
        const bool topA = (dA >= 0), topB = (dB >= 0);
        int eA = topA ? dA + 1 : -dA;
        int eB = topB ? dB + 1 : -dB;
        const int sgnA = topA ? 0 : (int)0x80000000;
        const int sgnB = topB ? 0 : (int)0x80000000;
        FOLD(vA, tA, topA)
        FOLD(vB, tB, topB)
        // (+INF sentinels: top -> excluded; bottom -> fold to -INF, never
        //  selected since e <= #real candidates.)

        float medA = tA, medB = tB;               // provably overwritten
        bool doneA = false, doneB = false;
#pragma unroll 1
        for (int r = 0; r < 300 && !(doneA && doneB); ++r) {
            float pA = doneA ? ninf : tree8(vA);
            float pB = doneB ? ninf : tree8(vB);
            pA = fmaxf(pA, bperm32(pA, axor32));  // halves now symmetric
            pB = fmaxf(pB, bperm32(pB, axor32));
            float m = (lane < 32) ? pA : pB;      // pack A|B, one shared reduce
            m = half_bfly(m);
            const float mA = rdlane(m, 0);
            const float mB = rdlane(m, 32);
            PEELSTEP(vA, eA, sgnA, medA, doneA, mA)
            PEELSTEP(vB, eB, sgnB, medB, doneB, mB)
        }
        tprev = medB;                              // warm start for next pair

        // ---- blend + store ----
        const float xcA = img[y * (WW * CHN) + xA * CHN];
        const float xcB = img[y * (WW * CHN) + xB * CHN];
        if (lane == 0) {
            outp[y * (WW * CHN) + xA * CHN] = medA + f * (xcA - medA);
            outp[y * (WW * CHN) + xB * CHN] = medB + f * (xcB - medB);
        }
    }
}

extern "C" void kernel_launch(void* const* d_in, const int* in_sizes, int n_in,
                              void* d_out, int out_size, void* d_ws, size_t ws_size,
                              hipStream_t stream) {
    const float* in    = (const float*)d_in[0];
    const float* blend = (const float*)d_in[1];
    float* out = (float*)d_out;

    const int nblocks = NGROUPS / 4;           // 9408, one group per wave
    median_blend_kernel<<<nblocks, 256, 0, stream>>>(in, blend, out);
}

// Round 9
// 155.921 us; speedup vs baseline: 3.7841x; 1.1345x over previous
//
#include <hip/hip_runtime.h>

// Median filter (k=22, REFLECT) + blend, NHWC (2,224,224,3) fp32.
// One wave per 8 consecutive-x pixels, processed as 4 PAIRS in lockstep.
// Window (484) in 8 regs/lane; ballot counting.
// V9 = V4 (113.8us, the proven best) + exactly three sign-safe deltas:
//  - BRACKETED NEWTON probes: V4's lo/hi bracket + midpoint fallback +
//    degenerate exit kept verbatim (the bracket is the convergence
//    guarantee — V6/V7/V8 proved the bracket-free walk oscillates/diverges
//    when local density > 2x average, regardless of DT), but the
//    interpolation math (cvt,rcp,mul + clo/chi state) is replaced by the
//    cheaper constant-slope step tn = fma(d, -1/AREA, t) clamped to (lo,hi);
//  - e==1 FAST PATH in the peel (absmax-0 proven 3x): the wave max IS the
//    answer; skip eq-ballots/purge. q-counting only when e>1 (exact w/ dups);
//  - BYTE-OFFSET gather (proven): pre-scaled voffB + wave-uniform char* base.
// DT=2, pair lockstep, one group/wave (9408 blocks) — all V4-proven.
// Extraction core (proven absmax 0): pair-packed sign-folded max-peel with
// in-lane tree + bpermute-xor32 + ONE shared 5-stage ds_swizzle butterfly
// (imm XOR patterns, zero address VALU) + readlane broadcast.

#define HH 224
#define WW 224
#define CHN 3
#define KK 22
#define PT 10            // pad top/left; bottom/right = 11
#define AREA (KK * KK)   // 484
#define RANK 242         // median = 242nd smallest (1-indexed)
#define PXW 8
#define XGS (WW / PXW)   // 28
#define DT 2             // stop probing when |count-RANK| <= DT
#define NGROUPS (2 * CHN * HH * XGS)   // 37632
#define XSB (CHN * 4)    // bytes per x-step (12)

#define INFF  __int_as_float(0x7f800000)
#define NINFF __int_as_float(0xff800000)

__device__ __forceinline__ int reflect224(int g) {
    int a = abs(g);
    return min(a, 2 * (HH - 1) - a);
}

__device__ __forceinline__ int count8(const float v[8], float t) {
    int c = 0;
#pragma unroll
    for (int i = 0; i < 8; ++i)
        c += __popcll(__ballot(v[i] < t));
    return c;
}

// in-lane tree max over the 8 window regs
__device__ __forceinline__ float tree8(const float v[8]) {
    return fmaxf(fmaxf(fmaxf(v[0], v[1]), fmaxf(v[2], v[3])),
                 fmaxf(fmaxf(v[4], v[5]), fmaxf(v[6], v[7])));
}

// butterfly max within each 32-lane half (ds_swizzle BitMode XOR patterns:
// offset = (xor<<10) | 0x1F, no address VALU). Halves reduce independently.
__device__ __forceinline__ float half_bfly(float m) {
    m = fmaxf(m, __int_as_float(__builtin_amdgcn_ds_swizzle(__float_as_int(m), 0x401F))); // ^16
    m = fmaxf(m, __int_as_float(__builtin_amdgcn_ds_swizzle(__float_as_int(m), 0x201F))); // ^8
    m = fmaxf(m, __int_as_float(__builtin_amdgcn_ds_swizzle(__float_as_int(m), 0x101F))); // ^4
    m = fmaxf(m, __int_as_float(__builtin_amdgcn_ds_swizzle(__float_as_int(m), 0x081F))); // ^2
    m = fmaxf(m, __int_as_float(__builtin_amdgcn_ds_swizzle(__float_as_int(m), 0x041F))); // ^1
    return m;
}

__device__ __forceinline__ float bperm32(float x, int axor32) {
    return __int_as_float(
        __builtin_amdgcn_ds_bpermute(axor32, __float_as_int(x)));
}

__device__ __forceinline__ float rdlane(float x, int l) {
    return __int_as_float(__builtin_amdgcn_readlane(__float_as_int(x), l));
}

// voffB holds BYTE offsets: gy*WW*CHN*4 + col*CHN*4 (vertical reflect baked)
__device__ __forceinline__ void gather(float v[8], const char* __restrict__ imgb,
                                       const int voffB[8], int lane, int x) {
    if (x >= PT && x <= WW - 1 - (KK - 1 - PT)) {      // interior: x in [10,212]
        const char* base = imgb + (x - PT) * XSB;      // wave-uniform base
#pragma unroll
        for (int i = 0; i < 8; ++i)
            v[i] = *(const float*)(base + voffB[i]);
    } else {
#pragma unroll
        for (int i = 0; i < 8; ++i) {
            int s   = i * 64 + lane;
            int se  = min(s, AREA - 1);
            int row = se / KK;
            int col = se - row * KK;
            int rowB = voffB[i] - col * XSB;
            int gx  = reflect224(x - PT + col);
            v[i] = *(const float*)(imgb + rowB + gx * XSB);
        }
    }
    v[7] = (lane < AREA - 448) ? v[7] : INFF;          // slots >= 484 -> +INF
}

// one bracketed-Newton probe step (V4's bracket, constant-slope step)
#define PROBE(vX, tX, dX, loX, hiX, actX)               \
    if (actX) {                                         \
        if (dX > 0) hiX = tX; else loX = tX;            \
        float tn_ = fmaf((float)dX, NINV, tX);          \
        if (!(tn_ > loX && tn_ < hiX)) tn_ = 0.5f * (loX + hiX); \
        if (!(tn_ > loX && tn_ < hiX)) actX = false;    \
        else {                                          \
            tX = tn_;                                   \
            dX = count8(vX, tX) - RANK;                 \
            actX = (dX > DT || dX < -DT);               \
        }                                               \
    }

// sign-fold in place: top (d>=0) keeps {v<t}; bottom keeps -{v>=t}
#define FOLD(vX, tX, topX)                                                   \
    if (topX) {                                                              \
        _Pragma("unroll")                                                    \
        for (int i_ = 0; i_ < 8; ++i_)                                       \
            vX[i_] = (vX[i_] < tX) ? vX[i_] : ninf;                          \
    } else {                                                                 \
        _Pragma("unroll")                                                    \
        for (int i_ = 0; i_ < 8; ++i_)                                       \
            vX[i_] = (vX[i_] < tX) ? ninf : -vX[i_];                         \
    }

// one peel resolution step for one pixel given its wave max mX
#define PEELSTEP(vX, eX, sgnX, medX, doneX, mX)                              \
    if (!doneX) {                                                            \
        if (eX == 1) {                                                       \
            medX = __int_as_float(__float_as_int(mX) ^ sgnX);                \
            doneX = true;                                                    \
        } else {                                                             \
            int q_ = 0;                                                      \
            _Pragma("unroll")                                                \
            for (int i_ = 0; i_ < 8; ++i_)                                   \
                q_ += __popcll(__ballot(vX[i_] == mX));                      \
            if (eX <= q_) {                                                  \
                medX = __int_as_float(__float_as_int(mX) ^ sgnX);            \
                doneX = true;                                                \
            } else {                                                         \
                eX -= q_;                                                    \
                _Pragma("unroll")                                            \
                for (int i_ = 0; i_ < 8; ++i_)                               \
                    vX[i_] = (vX[i_] == mX) ? ninf : vX[i_];                 \
            }                                                                \
        }                                                                    \
    }

__global__ __launch_bounds__(256)
void median_blend_kernel(const float* __restrict__ in,
                         const float* __restrict__ blend,
                         float* __restrict__ out) {
    const int lane = threadIdx.x & 63;
    const int wid  = threadIdx.x >> 6;
    const int wg = blockIdx.x * 4 + wid;        // wave-uniform group id
    // wg = ((b*CHN + c)*HH + y)*XGS + xg
    const int xg = wg % XGS;
    const int t1 = wg / XGS;
    const int y  = t1 % HH;
    const int t2 = t1 / HH;
    const int c  = t2 % CHN;
    const int b  = t2 / CHN;

    const float f = blend[0];
    const float* img  = in  + (size_t)b * (HH * WW * CHN) + c;
    float*       outp = out + (size_t)b * (HH * WW * CHN) + c;
    const char*  imgb = (const char*)img;

    // per-wave lane constants: BYTE voff = gy*2688 + col*12
    int voffB[8];
#pragma unroll
    for (int i = 0; i < 8; ++i) {
        int s   = i * 64 + lane;
        int se  = min(s, AREA - 1);
        int row = se / KK;
        int col = se - row * KK;
        int gy  = reflect224(y - PT + row);
        voffB[i] = gy * (WW * XSB) + col * XSB;
    }

    const int axor32 = (lane ^ 32) << 2;        // hoisted bpermute byte addr
    const float ninf = NINFF;
    const float NINV = -1.0f / (float)AREA;     // Newton slope: -1/484

    const int x0 = xg * PXW;
    float tprev = 0.5f;

#pragma unroll 1
    for (int j = 0; j < PXW; j += 2) {
        const int xA = x0 + j;
        const int xB = xA + 1;

        float vA[8], vB[8];
        gather(vA, imgb, voffB, lane, xA);
        gather(vB, imgb, voffB, lane, xB);

        // ---- warm-started bracketed-Newton probes, pair lockstep ----
        float tA = tprev, tB = tprev;
        int dA = count8(vA, tA) - RANK;
        int dB = count8(vB, tB) - RANK;
        float loA = 0.0f, hiA = 1.0f, loB = 0.0f, hiB = 1.0f;
        bool actA = (dA > DT || dA < -DT), actB = (dB > DT || dB < -DT);
#pragma unroll 1
        for (int it = 0; it < 16 && (actA || actB); ++it) {
            PROBE(vA, tA, dA, loA, hiA, actA)
            PROBE(vB, tB, dB, loB, hiB, actB)
        }

        // ---- pair-packed sign-folded max-peel ----
        // top (d>=0): (d+1)-th largest of {v<t}; bottom: (-d)-th smallest of
        // {v>=t} == peel max of -v. Exact for any (t,d).
        const bool topA = (dA >= 0), topB = (dB >= 0);
        int eA = topA ? dA + 1 : -dA;
        int eB = topB ? dB + 1 : -dB;
        const int sgnA = topA ? 0 : (int)0x80000000;
        const int sgnB = topB ? 0 : (int)0x80000000;
        FOLD(vA, tA, topA)
        FOLD(vB, tB, topB)
        // (+INF sentinels: top -> excluded; bottom -> fold to -INF, never
        //  selected since e <= #real candidates.)

        float medA = tA, medB = tB;               // provably overwritten
        bool doneA = false, doneB = false;
#pragma unroll 1
        for (int r = 0; r < 300 && !(doneA && doneB); ++r) {
            float pA = doneA ? ninf : tree8(vA);
            float pB = doneB ? ninf : tree8(vB);
            pA = fmaxf(pA, bperm32(pA, axor32));  // halves now symmetric
            pB = fmaxf(pB, bperm32(pB, axor32));
            float m = (lane < 32) ? pA : pB;      // pack A|B, one shared reduce
            m = half_bfly(m);
            const float mA = rdlane(m, 0);
            const float mB = rdlane(m, 32);
            PEELSTEP(vA, eA, sgnA, medA, doneA, mA)
            PEELSTEP(vB, eB, sgnB, medB, doneB, mB)
        }
        tprev = medB;                              // warm start for next pair

        // ---- blend + store ----
        const float xcA = img[y * (WW * CHN) + xA * CHN];
        const float xcB = img[y * (WW * CHN) + xB * CHN];
        if (lane == 0) {
            outp[y * (WW * CHN) + xA * CHN] = medA + f * (xcA - medA);
            outp[y * (WW * CHN) + xB * CHN] = medB + f * (xcB - medB);
        }
    }
}

extern "C" void kernel_launch(void* const* d_in, const int* in_sizes, int n_in,
                              void* d_out, int out_size, void* d_ws, size_t ws_size,
                              hipStream_t stream) {
    const float* in    = (const float*)d_in[0];
    const float* blend = (const float*)d_in[1];
    float* out = (float*)d_out;

    const int nblocks = NGROUPS / 4;           // 9408, one group per wave
    median_blend_kernel<<<nblocks, 256, 0, stream>>>(in, blend, out);
}